// Round 15
// baseline (70.646 us; speedup 1.0000x reference)
//
#include <hip/hip_runtime.h>

// LightPrompt inner_structure_update (dense form), MI355X gfx950.
// Outputs (f32, concat): x[4096,128] | adj[4096,4096] | edge_attr[4096,4096,4]
// Store floor ~49us (337.6 MB @ ~6.9 TB/s fill rate).
//
// R15 vs R14 (65.7us): timeline model says 65.7 = C1+S1+C2+S2 (9+23.7+9+23.7)
// -- round-1 stores and round-2 compute do NOT overlap. Fix: persistent
// 2-tile blocks, grid 1024 = exactly 4 blocks/CU (one residency round).
// Per block: tile0 (j0a) k-loop -> immediate adj0 (Ds transpose, small) ->
// tile1 (j0b=j0a+64) k-loop STATICALLY UNROLLED with tile0's bulky attr
// epilogue interleaved one rt-quarter per kp (acc0 stays in regs, static
// indexing per rule #20) -> tile1 epilogue. Stores now stream during compute.
// attr mask uses the equivalent dot-threshold d>=logit(0.55)=0.2006707
// (sigmoid monotone; boundary-flip prob ~1e-11) so deferred quarters need
// no exp/rcp. adj keeps sim>=0.55 (sim already computed for its value).
// Structure otherwise R14: split-bf16 3-term MFMA (absmax 2.44e-4), NT
// stores (R13 A/B: NT > plain), adj via Ds full-line transpose, x fused.

typedef float  f32x4  __attribute__((ext_vector_type(4)));
typedef short  bf16x8 __attribute__((ext_vector_type(8)));
typedef unsigned short u16x4 __attribute__((ext_vector_type(4)));

static constexpr int Tn = 4096;
static constexpr int Dm = 128;
static constexpr int En = 4;
static constexpr float THRE = 0.55f;
static constexpr float DTH  = 0.2006707f;  // logit(0.55)
static constexpr float SLOPE = 0.01f;

#define BM 128   // block rows (i)
#define BN 64    // per-tile cols (j); block covers 2 tiles = 128 cols
#define KS 32    // k chunk
#define LDH 40   // u16 per staging row: 80B stride, 2-way banks
#define LDS_D 68 // f32 per Ds row: 272B stride; writes 2-way, b128 reads min

__device__ __forceinline__ unsigned short bf16rn(float x) {
    unsigned int u = __float_as_uint(x);
    return (unsigned short)((u + 0x7FFFu + ((u >> 16) & 1u)) >> 16);
}
__device__ __forceinline__ float bf16tof(unsigned short h) {
    return __uint_as_float(((unsigned int)h) << 16);
}

__global__ __launch_bounds__(256) void lp_fused(const float* __restrict__ tokens,
                                                const float* __restrict__ edge_token,
                                                float* __restrict__ out) {
    __shared__ __align__(16) float smem_f[BM * LDS_D];
    unsigned short* Ah = (unsigned short*)smem_f;     // [BM*LDH]
    unsigned short* Al = Ah + BM * LDH;
    unsigned short* Bh = Al + BM * LDH;               // [BN*LDH]
    unsigned short* Bl = Bh + BN * LDH;
    float* Ds = smem_f;                               // [BM][LDS_D]

    const int tid = threadIdx.x;
    const int i0  = blockIdx.y * BM;
    const int j0a = blockIdx.x * 128;
    const int j0b = j0a + BN;

    // x output = tokens verbatim: first 512 of 1024 blocks.
    const int bid = blockIdx.y * (Tn / 128) + blockIdx.x;
    if (bid < 512) {
        reinterpret_cast<f32x4*>(out)[bid * 256 + tid] =
            reinterpret_cast<const f32x4*>(tokens)[bid * 256 + tid];
    }

    const int lane = tid & 63;
    const int w    = tid >> 6;
    const int wr   = w >> 1;
    const int wc   = w & 1;
    const int lr   = lane & 15;
    const int lk   = lane >> 4;

    int arw[4], ac4[4], brw[2], bc4[2];
#pragma unroll
    for (int p = 0; p < 4; ++p) {
        const int f = (p << 8) + tid;
        arw[p] = f >> 3;
        ac4[p] = (f & 7) << 2;
    }
#pragma unroll
    for (int p = 0; p < 2; ++p) {
        const int f = (p << 8) + tid;
        brw[p] = f >> 3;
        bc4[p] = (f & 7) << 2;
    }

    const float e0 = edge_token[0];
    const float e1 = edge_token[1];
    const float e2 = edge_token[2];
    const float e3 = edge_token[3];

    float* __restrict__ adj  = out + (size_t)Tn * Dm;
    float* __restrict__ attr = adj + (size_t)Tn * Tn;

    f32x4 acc0[4][2], acc1[4][2];
#pragma unroll
    for (int rt = 0; rt < 4; ++rt)
#pragma unroll
        for (int ct = 0; ct < 2; ++ct) { acc0[rt][ct] = (f32x4)(0.0f); acc1[rt][ct] = (f32x4)(0.0f); }

    // ================= tile0 k-loop (prefetched, rolled) =================
    f32x4 pa[4], pb[2];
#pragma unroll
    for (int p = 0; p < 4; ++p)
        pa[p] = *reinterpret_cast<const f32x4*>(tokens + (size_t)(i0 + arw[p]) * Dm + ac4[p]);
#pragma unroll
    for (int p = 0; p < 2; ++p)
        pb[p] = *reinterpret_cast<const f32x4*>(tokens + (size_t)(j0a + brw[p]) * Dm + bc4[p]);

#pragma unroll 1
    for (int kp = 0; kp < Dm / KS; ++kp) {
#pragma unroll
        for (int p = 0; p < 4; ++p) {
            u16x4 hi, lo;
#pragma unroll
            for (int e = 0; e < 4; ++e) {
                const unsigned short h = bf16rn(pa[p][e]);
                hi[e] = h; lo[e] = bf16rn(pa[p][e] - bf16tof(h));
            }
            *reinterpret_cast<u16x4*>(&Ah[arw[p] * LDH + ac4[p]]) = hi;
            *reinterpret_cast<u16x4*>(&Al[arw[p] * LDH + ac4[p]]) = lo;
        }
#pragma unroll
        for (int p = 0; p < 2; ++p) {
            u16x4 hi, lo;
#pragma unroll
            for (int e = 0; e < 4; ++e) {
                const unsigned short h = bf16rn(pb[p][e]);
                hi[e] = h; lo[e] = bf16rn(pb[p][e] - bf16tof(h));
            }
            *reinterpret_cast<u16x4*>(&Bh[brw[p] * LDH + bc4[p]]) = hi;
            *reinterpret_cast<u16x4*>(&Bl[brw[p] * LDH + bc4[p]]) = lo;
        }
        if (kp < Dm / KS - 1) {
            const int kb = (kp + 1) * KS;
#pragma unroll
            for (int p = 0; p < 4; ++p)
                pa[p] = *reinterpret_cast<const f32x4*>(tokens + (size_t)(i0 + arw[p]) * Dm + kb + ac4[p]);
#pragma unroll
            for (int p = 0; p < 2; ++p)
                pb[p] = *reinterpret_cast<const f32x4*>(tokens + (size_t)(j0a + brw[p]) * Dm + kb + bc4[p]);
        }
        __syncthreads();

        bf16x8 afh[4], afl[4], bfh[2], bfl[2];
#pragma unroll
        for (int rt = 0; rt < 4; ++rt) {
            const int row = (wr << 6) + (rt << 4) + lr;
            afh[rt] = *reinterpret_cast<const bf16x8*>(&Ah[row * LDH + (lk << 3)]);
            afl[rt] = *reinterpret_cast<const bf16x8*>(&Al[row * LDH + (lk << 3)]);
        }
#pragma unroll
        for (int ct = 0; ct < 2; ++ct) {
            const int col = (wc << 5) + (ct << 4) + lr;
            bfh[ct] = *reinterpret_cast<const bf16x8*>(&Bh[col * LDH + (lk << 3)]);
            bfl[ct] = *reinterpret_cast<const bf16x8*>(&Bl[col * LDH + (lk << 3)]);
        }
#pragma unroll
        for (int rt = 0; rt < 4; ++rt)
#pragma unroll
            for (int ct = 0; ct < 2; ++ct) {
                acc0[rt][ct] = __builtin_amdgcn_mfma_f32_16x16x32_bf16(afh[rt], bfh[ct], acc0[rt][ct], 0, 0, 0);
                acc0[rt][ct] = __builtin_amdgcn_mfma_f32_16x16x32_bf16(afh[rt], bfl[ct], acc0[rt][ct], 0, 0, 0);
                acc0[rt][ct] = __builtin_amdgcn_mfma_f32_16x16x32_bf16(afl[rt], bfh[ct], acc0[rt][ct], 0, 0, 0);
            }
        __syncthreads();
    }

    // ============ tile0 immediate epilogue: adj0 only (via Ds) ============
#pragma unroll
    for (int rt = 0; rt < 4; ++rt)
#pragma unroll
        for (int ct = 0; ct < 2; ++ct) {
            const int jl = (wc << 5) + (ct << 4) + lr;
#pragma unroll
            for (int reg = 0; reg < 4; ++reg) {
                const int il = (wr << 6) + (rt << 4) + (lk << 2) + reg;
                const float d = acc0[rt][ct][reg];
                const float sim = __builtin_amdgcn_rcpf(1.0f + __expf(-d));
                Ds[il * LDS_D + jl] = (sim >= THRE) ? sim : 0.0f;
            }
        }
    __syncthreads();
    {
        const int c4 = lr << 2;
#pragma unroll
        for (int s = 0; s < 8; ++s) {
            const int row = (w << 5) + (s << 2) + lk;
            const f32x4 v = *reinterpret_cast<const f32x4*>(&Ds[row * LDS_D + c4]);
            __builtin_nontemporal_store(v,
                reinterpret_cast<f32x4*>(adj + (size_t)(i0 + row) * Tn + j0a + c4));
        }
    }
    __syncthreads();   // Ds dead before tile1 staging overwrites it

    // ====== tile1 k-loop (unrolled) with deferred attr0 quarters ======
#pragma unroll
    for (int kp = 0; kp < Dm / KS; ++kp) {
        const int kbase = kp * KS;
#pragma unroll
        for (int p = 0; p < 4; ++p) {
            const f32x4 v = *reinterpret_cast<const f32x4*>(
                tokens + (size_t)(i0 + arw[p]) * Dm + kbase + ac4[p]);
            u16x4 hi, lo;
#pragma unroll
            for (int e = 0; e < 4; ++e) {
                const unsigned short h = bf16rn(v[e]);
                hi[e] = h; lo[e] = bf16rn(v[e] - bf16tof(h));
            }
            *reinterpret_cast<u16x4*>(&Ah[arw[p] * LDH + ac4[p]]) = hi;
            *reinterpret_cast<u16x4*>(&Al[arw[p] * LDH + ac4[p]]) = lo;
        }
#pragma unroll
        for (int p = 0; p < 2; ++p) {
            const f32x4 v = *reinterpret_cast<const f32x4*>(
                tokens + (size_t)(j0b + brw[p]) * Dm + kbase + bc4[p]);
            u16x4 hi, lo;
#pragma unroll
            for (int e = 0; e < 4; ++e) {
                const unsigned short h = bf16rn(v[e]);
                hi[e] = h; lo[e] = bf16rn(v[e] - bf16tof(h));
            }
            *reinterpret_cast<u16x4*>(&Bh[brw[p] * LDH + bc4[p]]) = hi;
            *reinterpret_cast<u16x4*>(&Bl[brw[p] * LDH + bc4[p]]) = lo;
        }
        __syncthreads();

        {
            bf16x8 bfh[2], bfl[2];
#pragma unroll
            for (int ct = 0; ct < 2; ++ct) {
                const int col = (wc << 5) + (ct << 4) + lr;
                bfh[ct] = *reinterpret_cast<const bf16x8*>(&Bh[col * LDH + (lk << 3)]);
                bfl[ct] = *reinterpret_cast<const bf16x8*>(&Bl[col * LDH + (lk << 3)]);
            }
#pragma unroll
            for (int rt = 0; rt < 4; ++rt) {
                const int row = (wr << 6) + (rt << 4) + lr;
                const bf16x8 afh = *reinterpret_cast<const bf16x8*>(&Ah[row * LDH + (lk << 3)]);
                const bf16x8 afl = *reinterpret_cast<const bf16x8*>(&Al[row * LDH + (lk << 3)]);
#pragma unroll
                for (int ct = 0; ct < 2; ++ct) {
                    acc1[rt][ct] = __builtin_amdgcn_mfma_f32_16x16x32_bf16(afh, bfh[ct], acc1[rt][ct], 0, 0, 0);
                    acc1[rt][ct] = __builtin_amdgcn_mfma_f32_16x16x32_bf16(afh, bfl[ct], acc1[rt][ct], 0, 0, 0);
                    acc1[rt][ct] = __builtin_amdgcn_mfma_f32_16x16x32_bf16(afl, bfh[ct], acc1[rt][ct], 0, 0, 0);
                }
            }
        }

        // Deferred attr0 quarter rt=kp (static acc0 index): stores stream
        // while other waves run MFMA/staging.
#pragma unroll
        for (int ct = 0; ct < 2; ++ct) {
            const int jl = (wc << 5) + (ct << 4) + lr;
            const int j = j0a + jl;
#pragma unroll
            for (int reg = 0; reg < 4; ++reg) {
                const int il = (wr << 6) + (kp << 4) + (lk << 2) + reg;
                const float d = acc0[kp][ct][reg];
                const float m = (d >= DTH) ? 1.0f : 0.0f;
                f32x4 at;
                float v;
                v = d * e0; at.x = (v > 0.0f ? v : SLOPE * v) * m;
                v = d * e1; at.y = (v > 0.0f ? v : SLOPE * v) * m;
                v = d * e2; at.z = (v > 0.0f ? v : SLOPE * v) * m;
                v = d * e3; at.w = (v > 0.0f ? v : SLOPE * v) * m;
                __builtin_nontemporal_store(at,
                    reinterpret_cast<f32x4*>(attr + ((size_t)(i0 + il) * Tn + j) * En));
            }
        }
        __syncthreads();
    }

    // ================= tile1 epilogue: attr1 + adj1 =================
#pragma unroll
    for (int rt = 0; rt < 4; ++rt)
#pragma unroll
        for (int ct = 0; ct < 2; ++ct) {
            const int jl = (wc << 5) + (ct << 4) + lr;
            const int j = j0b + jl;
#pragma unroll
            for (int reg = 0; reg < 4; ++reg) {
                const int il = (wr << 6) + (rt << 4) + (lk << 2) + reg;
                const float d = acc1[rt][ct][reg];
                const float sim = __builtin_amdgcn_rcpf(1.0f + __expf(-d));
                Ds[il * LDS_D + jl] = (sim >= THRE) ? sim : 0.0f;
                const float m = (d >= DTH) ? 1.0f : 0.0f;
                f32x4 at;
                float v;
                v = d * e0; at.x = (v > 0.0f ? v : SLOPE * v) * m;
                v = d * e1; at.y = (v > 0.0f ? v : SLOPE * v) * m;
                v = d * e2; at.z = (v > 0.0f ? v : SLOPE * v) * m;
                v = d * e3; at.w = (v > 0.0f ? v : SLOPE * v) * m;
                __builtin_nontemporal_store(at,
                    reinterpret_cast<f32x4*>(attr + ((size_t)(i0 + il) * Tn + j) * En));
            }
        }
    __syncthreads();
    {
        const int c4 = lr << 2;
#pragma unroll
        for (int s = 0; s < 8; ++s) {
            const int row = (w << 5) + (s << 2) + lk;
            const f32x4 v = *reinterpret_cast<const f32x4*>(&Ds[row * LDS_D + c4]);
            __builtin_nontemporal_store(v,
                reinterpret_cast<f32x4*>(adj + (size_t)(i0 + row) * Tn + j0b + c4));
        }
    }
}

extern "C" void kernel_launch(void* const* d_in, const int* in_sizes, int n_in,
                              void* d_out, int out_size, void* d_ws, size_t ws_size,
                              hipStream_t stream) {
    const float* tokens     = (const float*)d_in[0];  // [1,4096,128] f32
    const float* edge_token = (const float*)d_in[1];  // [1,4] f32
    float* out = (float*)d_out;

    hipLaunchKernelGGL(lp_fused, dim3(Tn / 128, Tn / BM), dim3(256), 0, stream,
                       tokens, edge_token, out);
}

// Round 16
// 65.654 us; speedup vs baseline: 1.0760x; 1.0760x over previous
//
#include <hip/hip_runtime.h>
#include <hip/hip_bf16.h>

// LightPrompt inner_structure_update (dense form), MI355X gfx950.
// Outputs (f32, concat): x[4096,128] | adj[4096,4096] | edge_attr[4096,4096,4]
// Store floor ~49us (337.6 MB @ ~6.9 TB/s fill rate).
//
// R16 = R14 (65.7us best; R15's persistent 2-tile regressed to 70.6 and is
// reverted) + ONE lever: the split-bf16 convert uses v_cvt_pk_bf16_f32 via
// the HIP API (__float22bfloat162_rn / __bfloat1622float2) -> 12 ops per
// f32x4 vs ~40 for the manual integer-RN path. Convert was the largest item
// (~5us/round) on the barrier-locked compute critical path (~9us/round).
// Same RNE rounding -> bit-identical absmax 2.44e-4.
// Kept from prior A/Bs: NT stores (R13: NT 66.6 < plain 68.9), async-stage
// prefetch + rcpf sigmoid (R14), adj via Ds full-line transpose (R12),
// split-bf16 3-term MFMA dot (R10), fused x-copy.

typedef float  f32x4  __attribute__((ext_vector_type(4)));
typedef short  bf16x8 __attribute__((ext_vector_type(8)));
typedef unsigned int uint2v __attribute__((ext_vector_type(2)));

static constexpr int Tn = 4096;
static constexpr int Dm = 128;
static constexpr int En = 4;
static constexpr float THRE = 0.55f;
static constexpr float SLOPE = 0.01f;

#define BM 128   // block rows (i)
#define BN 64    // block cols (j)
#define KS 32    // k chunk
#define LDH 40   // u16 per staging row: 80B stride (16B-aligned), 2-way banks
#define LDS_D 68 // f32 per Ds row: 272B stride; writes 2-way, b128 reads min

// Split one f32x4 into hi/lo bf16 pairs, packed as 2x u32 each (cvt_pk path).
__device__ __forceinline__ void split4(const f32x4 v, uint2v& hi, uint2v& lo) {
    const __hip_bfloat162 h0 = __float22bfloat162_rn(float2{v[0], v[1]});
    const __hip_bfloat162 h1 = __float22bfloat162_rn(float2{v[2], v[3]});
    const float2 f0 = __bfloat1622float2(h0);
    const float2 f1 = __bfloat1622float2(h1);
    const __hip_bfloat162 l0 = __float22bfloat162_rn(float2{v[0] - f0.x, v[1] - f0.y});
    const __hip_bfloat162 l1 = __float22bfloat162_rn(float2{v[2] - f1.x, v[3] - f1.y});
    hi[0] = *reinterpret_cast<const unsigned int*>(&h0);
    hi[1] = *reinterpret_cast<const unsigned int*>(&h1);
    lo[0] = *reinterpret_cast<const unsigned int*>(&l0);
    lo[1] = *reinterpret_cast<const unsigned int*>(&l1);
}

__global__ __launch_bounds__(256) void lp_fused(const float* __restrict__ tokens,
                                                const float* __restrict__ edge_token,
                                                float* __restrict__ out) {
    // 34816 B shared: staging arrays (30720 B) alias the front; Ds reuses it
    // after the k-loop's final barrier (staging dead by then).
    __shared__ __align__(16) float smem_f[BM * LDS_D];
    unsigned short* Ah = (unsigned short*)smem_f;     // [BM*LDH]
    unsigned short* Al = Ah + BM * LDH;               // [BM*LDH]
    unsigned short* Bh = Al + BM * LDH;               // [BN*LDH]
    unsigned short* Bl = Bh + BN * LDH;               // [BN*LDH]
    float* Ds = smem_f;                               // [BM][LDS_D]

    const int tid = threadIdx.x;
    const int i0 = blockIdx.y * BM;
    const int j0 = blockIdx.x * BN;

    // x output = tokens verbatim (131072 float4): first 512 of 2048 blocks.
    const int bid = blockIdx.y * (Tn / BN) + blockIdx.x;
    if (bid < 512) {
        reinterpret_cast<f32x4*>(out)[bid * 256 + tid] =
            reinterpret_cast<const f32x4*>(tokens)[bid * 256 + tid];
    }

    const int lane = tid & 63;
    const int w    = tid >> 6;   // wave 0..3
    const int wr   = w >> 1;     // row half (64 rows)
    const int wc   = w & 1;      // col half (32 cols)
    const int lr   = lane & 15;  // frag row/col within 16x16 tile
    const int lk   = lane >> 4;  // k quarter (8 bf16)

    // Per-thread staging coordinates (fixed across kp).
    int arw[4], ac4[4], brw[2], bc4[2];
#pragma unroll
    for (int p = 0; p < 4; ++p) {
        const int f = (p << 8) + tid;
        arw[p] = f >> 3;
        ac4[p] = (f & 7) << 2;
    }
#pragma unroll
    for (int p = 0; p < 2; ++p) {
        const int f = (p << 8) + tid;
        brw[p] = f >> 3;
        bc4[p] = (f & 7) << 2;
    }

    f32x4 acc[4][2];
#pragma unroll
    for (int rt = 0; rt < 4; ++rt)
#pragma unroll
        for (int ct = 0; ct < 2; ++ct) acc[rt][ct] = (f32x4)(0.0f);

    // Prefetch registers: kp's staging data loaded one iteration ahead.
    f32x4 pa[4], pb[2];
#pragma unroll
    for (int p = 0; p < 4; ++p)
        pa[p] = *reinterpret_cast<const f32x4*>(
            tokens + (size_t)(i0 + arw[p]) * Dm + ac4[p]);
#pragma unroll
    for (int p = 0; p < 2; ++p)
        pb[p] = *reinterpret_cast<const f32x4*>(
            tokens + (size_t)(j0 + brw[p]) * Dm + bc4[p]);

#pragma unroll 1
    for (int kp = 0; kp < Dm / KS; ++kp) {
        // Convert (cvt_pk) + LDS write; prev iter's trailing barrier ordered
        // these writes after all prior LDS reads.
#pragma unroll
        for (int p = 0; p < 4; ++p) {
            uint2v hi, lo;
            split4(pa[p], hi, lo);
            *reinterpret_cast<uint2v*>(&Ah[arw[p] * LDH + ac4[p]]) = hi;
            *reinterpret_cast<uint2v*>(&Al[arw[p] * LDH + ac4[p]]) = lo;
        }
#pragma unroll
        for (int p = 0; p < 2; ++p) {
            uint2v hi, lo;
            split4(pb[p], hi, lo);
            *reinterpret_cast<uint2v*>(&Bh[brw[p] * LDH + bc4[p]]) = hi;
            *reinterpret_cast<uint2v*>(&Bl[brw[p] * LDH + bc4[p]]) = lo;
        }
        // Issue next kp's loads now: latency hides under barrier+frags+MFMA.
        if (kp < Dm / KS - 1) {
            const int kb = (kp + 1) * KS;
#pragma unroll
            for (int p = 0; p < 4; ++p)
                pa[p] = *reinterpret_cast<const f32x4*>(
                    tokens + (size_t)(i0 + arw[p]) * Dm + kb + ac4[p]);
#pragma unroll
            for (int p = 0; p < 2; ++p)
                pb[p] = *reinterpret_cast<const f32x4*>(
                    tokens + (size_t)(j0 + brw[p]) * Dm + kb + bc4[p]);
        }
        __syncthreads();

        // Fragments: lane lr = tile row/col, lk*8 = k offset (16B b128 reads).
        bf16x8 afh[4], afl[4], bfh[2], bfl[2];
#pragma unroll
        for (int rt = 0; rt < 4; ++rt) {
            const int row = (wr << 6) + (rt << 4) + lr;
            afh[rt] = *reinterpret_cast<const bf16x8*>(&Ah[row * LDH + (lk << 3)]);
            afl[rt] = *reinterpret_cast<const bf16x8*>(&Al[row * LDH + (lk << 3)]);
        }
#pragma unroll
        for (int ct = 0; ct < 2; ++ct) {
            const int col = (wc << 5) + (ct << 4) + lr;
            bfh[ct] = *reinterpret_cast<const bf16x8*>(&Bh[col * LDH + (lk << 3)]);
            bfl[ct] = *reinterpret_cast<const bf16x8*>(&Bl[col * LDH + (lk << 3)]);
        }
#pragma unroll
        for (int rt = 0; rt < 4; ++rt)
#pragma unroll
            for (int ct = 0; ct < 2; ++ct) {
                acc[rt][ct] = __builtin_amdgcn_mfma_f32_16x16x32_bf16(
                    afh[rt], bfh[ct], acc[rt][ct], 0, 0, 0);
                acc[rt][ct] = __builtin_amdgcn_mfma_f32_16x16x32_bf16(
                    afh[rt], bfl[ct], acc[rt][ct], 0, 0, 0);
                acc[rt][ct] = __builtin_amdgcn_mfma_f32_16x16x32_bf16(
                    afl[rt], bfh[ct], acc[rt][ct], 0, 0, 0);
            }
        __syncthreads();   // also makes staging LDS dead -> Ds reuse safe
    }

    const float e0 = edge_token[0];
    const float e1 = edge_token[1];
    const float e2 = edge_token[2];
    const float e3 = edge_token[3];

    float* __restrict__ adj  = out + (size_t)Tn * Dm;
    float* __restrict__ attr = adj + (size_t)Tn * Tn;

    // C/D layout (m89-verified): col = lane&15, row = (lane>>4)*4 + reg.
    // attr direct NT (256B contiguous per 4-store cluster); sim*m into Ds.
#pragma unroll
    for (int rt = 0; rt < 4; ++rt) {
#pragma unroll
        for (int ct = 0; ct < 2; ++ct) {
            const f32x4 dv = acc[rt][ct];
            const int jl = (wc << 5) + (ct << 4) + lr;
            const int j = j0 + jl;
#pragma unroll
            for (int reg = 0; reg < 4; ++reg) {
                const int il = (wr << 6) + (rt << 4) + (lk << 2) + reg;
                const float d = dv[reg];
                const float sim = __builtin_amdgcn_rcpf(1.0f + __expf(-d));
                const float m = (sim >= THRE) ? 1.0f : 0.0f;
                Ds[il * LDS_D + jl] = sim * m;
                f32x4 at;
                float v;
                v = d * e0; at.x = (v > 0.0f ? v : SLOPE * v) * m;
                v = d * e1; at.y = (v > 0.0f ? v : SLOPE * v) * m;
                v = d * e2; at.z = (v > 0.0f ? v : SLOPE * v) * m;
                v = d * e3; at.w = (v > 0.0f ? v : SLOPE * v) * m;
                __builtin_nontemporal_store(at,
                    reinterpret_cast<f32x4*>(attr + ((size_t)(i0 + il) * Tn + j) * En));
            }
        }
    }
    __syncthreads();

    // adj from Ds, row-major: per wave-instr 4 rows x 256B (2 full lines).
    const int c4 = lr << 2;
#pragma unroll
    for (int s = 0; s < 8; ++s) {
        const int row = (w << 5) + (s << 2) + lk;
        const f32x4 v = *reinterpret_cast<const f32x4*>(&Ds[row * LDS_D + c4]);
        __builtin_nontemporal_store(v,
            reinterpret_cast<f32x4*>(adj + (size_t)(i0 + row) * Tn + j0 + c4));
    }
}

extern "C" void kernel_launch(void* const* d_in, const int* in_sizes, int n_in,
                              void* d_out, int out_size, void* d_ws, size_t ws_size,
                              hipStream_t stream) {
    const float* tokens     = (const float*)d_in[0];  // [1,4096,128] f32
    const float* edge_token = (const float*)d_in[1];  // [1,4] f32
    float* out = (float*)d_out;

    hipLaunchKernelGGL(lp_fused, dim3(Tn / BN, Tn / BM), dim3(256), 0, stream,
                       tokens, edge_token, out);
}